// Round 1
// baseline (455.870 us; speedup 1.0000x reference)
//
#include <hip/hip_runtime.h>

// VCDN cross-feature matvec: out[c] = relu(W[c,:] @ cfdt + b[c])
// cfdt[(a*2304)+t] = p01[a] * p23[t]  (rank-1, never materialized)
// Memory floor: W = 339.7 MB fp32 read once ~ 52 us @ 6.5 TB/s achieved.
// Round 5 theory: total 416us = ~208us harness ws-poison fill (fixed)
//                 + ~205us vcdn_main + ~3us finalize.
// vcdn_main at 205us = 1.7 TB/s (26% of achievable) despite coalesced 1KB
// wave-loads -> suspect the 85-VGPR cap from __launch_bounds__(256,6)
// (spill / load-serialization), plus NT-load hint as secondary suspect.
// Fix: launch_bounds(256,4) -> 128-VGPR cap, grid 1024 = exactly 4
// blocks/CU (perfect residency, zero tail, 16 waves/CU -- in-flight
// arithmetic says ~10KB/CU suffices for 6.5TB/s; we have >100KB),
// 9 rows/wave, 3 acc chains, plain cached loads (drop NT).

#define N_CLASSES 16
#define VIEW_DIM  48
#define P         2304            // 48*48 (row length in floats)
#define ROW_F4    (P / 4)         // 576 float4 per row
#define ROWS_PER_BLOCK 36
#define CHUNKS    (P / ROWS_PER_BLOCK)   // 64 blocks per class -> grid 1024
#define ROWS_PER_WAVE  9          // 4 waves per block
#define BLOCK     256
#define ITERS     (ROW_F4 / 64)   // 9 float4 per lane per row

typedef float v4f __attribute__((ext_vector_type(4)));

__global__ __launch_bounds__(BLOCK, 4) void vcdn_main(
        const float* __restrict__ x,
        const float* __restrict__ W,
        float* __restrict__ ws) {
    __shared__ float p23[P];

    const float* x0 = x;
    const float* x1 = x + VIEW_DIM;
    const float* x2 = x + 2 * VIEW_DIM;
    const float* x3 = x + 3 * VIEW_DIM;

    for (int t = threadIdx.x; t < P; t += BLOCK) {
        int i = t / VIEW_DIM;
        int j = t - i * VIEW_DIM;
        p23[t] = x2[i] * x3[j];
    }
    __syncthreads();

    const int c     = blockIdx.x / CHUNKS;
    const int chunk = blockIdx.x - c * CHUNKS;
    const int wid   = threadIdx.x >> 6;
    const int lane  = threadIdx.x & 63;

    // This lane's 9 loop-invariant p23 fragments -> registers (36 VGPRs).
    const v4f* q4 = (const v4f*)p23;
    v4f q[ITERS];
#pragma unroll
    for (int it = 0; it < ITERS; ++it) q[it] = q4[it * 64 + lane];

    const int row0 = chunk * ROWS_PER_BLOCK + wid * ROWS_PER_WAVE;
    float acc0 = 0.0f, acc1 = 0.0f, acc2 = 0.0f;  // 3 chains for ILP

#pragma unroll
    for (int r = 0; r < ROWS_PER_WAVE; ++r) {
        const int a = row0 + r;                 // row index in [0, 2304)
        const int i = a / VIEW_DIM;
        const int j = a - i * VIEW_DIM;
        const float s01 = x0[i] * x1[j];        // wave-uniform scalar

        const v4f* Wrow =
            (const v4f*)(W + (size_t)c * (size_t)P * P + (size_t)a * P);

        float racc = 0.0f;
#pragma unroll
        for (int it = 0; it < ITERS; ++it) {
            v4f w = Wrow[it * 64 + lane];       // plain cached load
            racc += w.x * q[it].x + w.y * q[it].y + w.z * q[it].z + w.w * q[it].w;
        }
        if      (r % 3 == 0) acc0 += s01 * racc;
        else if (r % 3 == 1) acc1 += s01 * racc;
        else                 acc2 += s01 * racc;
    }
    float acc = acc0 + acc1 + acc2;

    // wave64 reduce, then 4 waves -> 1 value, pure store
    for (int off = 32; off; off >>= 1)
        acc += __shfl_down(acc, off, 64);

    __shared__ float wsum[BLOCK / 64];
    if (lane == 0) wsum[wid] = acc;
    __syncthreads();
    if (threadIdx.x == 0)
        ws[c * CHUNKS + chunk] = wsum[0] + wsum[1] + wsum[2] + wsum[3];
}

__global__ void vcdn_finalize(const float* __restrict__ ws,
                              const float* __restrict__ b,
                              float* __restrict__ out) {
    __shared__ float s[BLOCK];
    const int t   = threadIdx.x;
    const int c   = t >> 4;        // 16 threads per class
    const int sub = t & 15;
    float sum = 0.0f;
    for (int k = sub; k < CHUNKS; k += 16)     // 64/16 = 4 partials each
        sum += ws[c * CHUNKS + k];
    s[t] = sum;
    __syncthreads();
    if (t < N_CLASSES) {
        float tot = 0.0f;
#pragma unroll
        for (int k = 0; k < 16; ++k) tot += s[t * 16 + k];
        tot += b[t];
        out[t] = tot > 0.0f ? tot : 0.0f;
    }
}

extern "C" void kernel_launch(void* const* d_in, const int* in_sizes, int n_in,
                              void* d_out, int out_size, void* d_ws, size_t ws_size,
                              hipStream_t stream) {
    const float* x = (const float*)d_in[0];   // (4, 48) fp32
    const float* W = (const float*)d_in[1];   // (16, D) fp32
    const float* b = (const float*)d_in[2];   // (16,) fp32
    float* out = (float*)d_out;               // (16,) fp32
    float* ws  = (float*)d_ws;                // partials: 16*64 floats

    vcdn_main<<<N_CLASSES * CHUNKS, BLOCK, 0, stream>>>(x, W, ws);
    vcdn_finalize<<<1, BLOCK, 0, stream>>>(ws, b, out);
}

// Round 2
// 448.447 us; speedup vs baseline: 1.0166x; 1.0166x over previous
//
#include <hip/hip_runtime.h>

// VCDN cross-feature matvec: out[c] = relu(W[c,:] @ cfdt + b[c])
// cfdt[(a*2304)+t] = p01[a] * p23[t]  (rank-1, never materialized)
// Memory floor: W = 339.7 MB fp32 read once ~ 52 us @ 6.5 TB/s achieved.
//
// Round 6 theory: rounds 0/1 ran the W-stream at 1.4-1.7 TB/s despite
// perfect coalescing; latency math rules out simple occupancy limits ->
// VGPR-path spill/serialization. Fix: take VGPRs out of the load path.
// Each wave streams its contiguous 54KB slice through a PRIVATE 6-slot
// x 1KB LDS ring via __builtin_amdgcn_global_load_lds (width 16), with
// counted s_waitcnt vmcnt(5) (never 0 in steady state). No __syncthreads
// in the hot loop (private rings). lgkmcnt(0) drain between ds_read and
// slot restage closes the DMA-overwrite hazard. ~60 VGPRs -> no spill at
// the 84-reg cap; 6 blocks/CU x 4 waves = 24 waves/CU, all co-resident.
// In-flight: 6KB/wave x 24 waves = 144KB/CU >> ~10KB needed for 6.5TB/s.

#define N_CLASSES 16
#define VIEW_DIM  48
#define P         2304                   // 48*48 (row length in floats)
#define ROWS_PER_BLOCK 24
#define CHUNKS    (P / ROWS_PER_BLOCK)   // 96 blocks per class -> grid 1536
#define ROWS_PER_WAVE  6                 // 4 waves per block
#define BLOCK     256
#define NWAVES    4
#define CPR       9                      // 1KB chunks per row (2304 floats / 256)
#define TOTC      (ROWS_PER_WAVE * CPR)  // 54 chunks per wave
#define DEPTH     6                      // ring slots == chunks in flight

typedef float v4f __attribute__((ext_vector_type(4)));

__device__ __forceinline__ void stage1k(const float* gsrc, float* lds_uniform) {
    // 64 lanes x 16B = 1KB direct-to-LDS, no VGPR destination.
    // LDS dest is wave-uniform base + lane*16 (m104 semantics); gsrc is per-lane.
    __builtin_amdgcn_global_load_lds(
        (const __attribute__((address_space(1))) unsigned int*)gsrc,
        (__attribute__((address_space(3))) unsigned int*)lds_uniform,
        16, 0, 0);
}

__global__ __launch_bounds__(BLOCK, 6) void vcdn_main(
        const float* __restrict__ x,
        const float* __restrict__ W,
        float* __restrict__ ws) {
    __shared__ float ring[NWAVES][DEPTH][256];   // 24 KB/block -> 6 blocks/CU fits 160KB

    const int c     = blockIdx.x / CHUNKS;
    const int chunk = blockIdx.x - c * CHUNKS;
    const int wid   = threadIdx.x >> 6;
    const int lane  = threadIdx.x & 63;

    const float* x0 = x;
    const float* x1 = x + VIEW_DIM;
    const float* x2 = x + 2 * VIEW_DIM;
    const float* x3 = x + 3 * VIEW_DIM;

    const int row0 = chunk * ROWS_PER_BLOCK + wid * ROWS_PER_WAVE;

    // Per-lane loop-invariant p23 fragments, computed directly into registers:
    // q[k][e] = x2[t/48]*x3[t%48], t = k*256 + lane*4 + e   (36 VGPRs)
    v4f q[CPR];
#pragma unroll
    for (int k = 0; k < CPR; ++k) {
#pragma unroll
        for (int e = 0; e < 4; ++e) {
            const int t = k * 256 + lane * 4 + e;
            const int i = t / VIEW_DIM;
            const int j = t - i * VIEW_DIM;
            q[k][e] = x2[i] * x3[j];
        }
    }

    // Per-row wave-uniform p01 scalars
    float s01[ROWS_PER_WAVE];
#pragma unroll
    for (int r = 0; r < ROWS_PER_WAVE; ++r) {
        const int a = row0 + r;
        const int i = a / VIEW_DIM;
        const int j = a - i * VIEW_DIM;
        s01[r] = x0[i] * x1[j];
    }

    // Wave's contiguous 54KB region of W (6 consecutive rows)
    const float* wbase = W + (size_t)c * (size_t)(P * P) + (size_t)row0 * P;
    float* myring = &ring[wid][0][0];

    // Counted-vmcnt soundness: drain the x-loads so stages are the only VMEM ops.
    asm volatile("s_waitcnt vmcnt(0)" ::: "memory");

    // Prologue: fill the ring (chunks 0..5 in flight)
#pragma unroll
    for (int m = 0; m < DEPTH; ++m)
        stage1k(wbase + m * 256 + lane * 4, myring + m * 256);

    float acc = 0.0f;
#pragma unroll
    for (int r = 0; r < ROWS_PER_WAVE; ++r) {
        float racc = 0.0f;
#pragma unroll
        for (int k = 0; k < CPR; ++k) {
            const int m    = r * CPR + k;        // unrolled-constant
            const int slot = m % DEPTH;
            // Wait until chunk m has landed: leave min(5, 53-m) in flight.
            const int wn = (TOTC - 1 - m) < (DEPTH - 1) ? (TOTC - 1 - m) : (DEPTH - 1);
            switch (wn) {  // constant-folds per unrolled iteration
                case 0: asm volatile("s_waitcnt vmcnt(0)" ::: "memory"); break;
                case 1: asm volatile("s_waitcnt vmcnt(1)" ::: "memory"); break;
                case 2: asm volatile("s_waitcnt vmcnt(2)" ::: "memory"); break;
                case 3: asm volatile("s_waitcnt vmcnt(3)" ::: "memory"); break;
                case 4: asm volatile("s_waitcnt vmcnt(4)" ::: "memory"); break;
                default: asm volatile("s_waitcnt vmcnt(5)" ::: "memory"); break;
            }
            // Read this lane's 16B of the chunk (conflict-free: contiguous 1KB)
            v4f w = *(const v4f*)(myring + slot * 256 + lane * 4);
            // Ensure the ds_read has RETIRED before the DMA overwrites the slot.
            asm volatile("s_waitcnt lgkmcnt(0)" ::: "memory");
            if (m < TOTC - DEPTH)
                stage1k(wbase + (m + DEPTH) * 256 + lane * 4, myring + slot * 256);
            racc += w.x * q[k].x + w.y * q[k].y + w.z * q[k].z + w.w * q[k].w;
        }
        acc += s01[r] * racc;
    }

    // wave64 reduce, then 4 waves -> 1 value, pure store
    for (int off = 32; off; off >>= 1)
        acc += __shfl_down(acc, off, 64);

    __shared__ float wsum[NWAVES];
    if (lane == 0) wsum[wid] = acc;
    __syncthreads();
    if (threadIdx.x == 0)
        ws[c * CHUNKS + chunk] = wsum[0] + wsum[1] + wsum[2] + wsum[3];
}

__global__ void vcdn_finalize(const float* __restrict__ ws,
                              const float* __restrict__ b,
                              float* __restrict__ out) {
    __shared__ float s[BLOCK];
    const int t   = threadIdx.x;
    const int c   = t >> 4;        // 16 threads per class
    const int sub = t & 15;
    float sum = 0.0f;
    for (int k = sub; k < CHUNKS; k += 16)     // 96/16 = 6 partials each
        sum += ws[c * CHUNKS + k];
    s[t] = sum;
    __syncthreads();
    if (t < N_CLASSES) {
        float tot = 0.0f;
#pragma unroll
        for (int k = 0; k < 16; ++k) tot += s[t * 16 + k];
        tot += b[t];
        out[t] = tot > 0.0f ? tot : 0.0f;
    }
}

extern "C" void kernel_launch(void* const* d_in, const int* in_sizes, int n_in,
                              void* d_out, int out_size, void* d_ws, size_t ws_size,
                              hipStream_t stream) {
    const float* x = (const float*)d_in[0];   // (4, 48) fp32
    const float* W = (const float*)d_in[1];   // (16, D) fp32
    const float* b = (const float*)d_in[2];   // (16,) fp32
    float* out = (float*)d_out;               // (16,) fp32
    float* ws  = (float*)d_ws;                // partials: 16*96 floats

    vcdn_main<<<N_CLASSES * CHUNKS, BLOCK, 0, stream>>>(x, W, ws);
    vcdn_finalize<<<1, BLOCK, 0, stream>>>(ws, b, out);
}

// Round 3
// 418.937 us; speedup vs baseline: 1.0882x; 1.0704x over previous
//
#include <hip/hip_runtime.h>

// VCDN cross-feature matvec: out[c] = relu(W[c,:] @ cfdt + b[c])
// cfdt[(a*2304)+bb] = p01[a] * p23[bb]  (rank-1, never materialized)
// Memory floor: W = 339.7 MB fp32 read once ~ 52 us @ 6.6 TB/s achieved.
//
// Round 7: RESTORE the round-0 kernel verbatim. Shadow model (fits r0-r2
// to <1.5 us): dur = fill1(207) + max(fill2(207), main_corun) + finalize(3).
// The timed region contains two ~207us harness poison fills (1.36 GB
// WRITE_SIZE each, 82% HBM peak); main co-runs with the second fill and
// is FREE as long as its co-run time stays under the fill's shadow.
// Round 0 (this kernel) was inside the shadow -> 416.5 us = the floor.
// Rounds 1/2 restructured the load path, slowed main's co-run share,
// and poked out of the shadow by exactly (main-207): +39/+32 us.
// Solo (rocprof serialized replay), this kernel is < 203 us cutoff
// (never in top-5), i.e. near the 52 us W-stream roofline.
// Floor = 2*fill + finalize ~ 414-417 us, harness-owned. Expect ~416.

#define N_CLASSES 16
#define VIEW_DIM  48
#define P         2304            // 48*48 (row length in floats)
#define ROW_F4    (P / 4)         // 576 float4 per row
#define ROWS_PER_BLOCK 24
#define CHUNKS    (P / ROWS_PER_BLOCK)   // 96 blocks per class -> grid 1536
#define ROWS_PER_WAVE  6          // 4 waves per block
#define BLOCK     256
#define ITERS     (ROW_F4 / 64)   // 9 float4 per lane per row

typedef float v4f __attribute__((ext_vector_type(4)));

__global__ __launch_bounds__(BLOCK, 6) void vcdn_main(
        const float* __restrict__ x,
        const float* __restrict__ W,
        float* __restrict__ ws) {
    __shared__ float p23[P];

    const float* x0 = x;
    const float* x1 = x + VIEW_DIM;
    const float* x2 = x + 2 * VIEW_DIM;
    const float* x3 = x + 3 * VIEW_DIM;

    for (int t = threadIdx.x; t < P; t += BLOCK) {
        int i = t / VIEW_DIM;
        int j = t - i * VIEW_DIM;
        p23[t] = x2[i] * x3[j];
    }
    __syncthreads();

    const int c     = blockIdx.x / CHUNKS;
    const int chunk = blockIdx.x - c * CHUNKS;
    const int wid   = threadIdx.x >> 6;
    const int lane  = threadIdx.x & 63;

    // This lane's 9 loop-invariant p23 fragments -> registers (36 VGPRs).
    const v4f* q4 = (const v4f*)p23;
    v4f q[ITERS];
#pragma unroll
    for (int it = 0; it < ITERS; ++it) q[it] = q4[it * 64 + lane];

    const int row0 = chunk * ROWS_PER_BLOCK + wid * ROWS_PER_WAVE;
    float acc0 = 0.0f, acc1 = 0.0f;   // two chains, alternate rows

#pragma unroll
    for (int r = 0; r < ROWS_PER_WAVE; ++r) {
        const int a = row0 + r;                 // row index in [0, 2304)
        const int i = a / VIEW_DIM;
        const int j = a - i * VIEW_DIM;
        const float s01 = x0[i] * x1[j];        // wave-uniform scalar

        const v4f* Wrow =
            (const v4f*)(W + (size_t)c * (size_t)P * P + (size_t)a * P);

        float racc = 0.0f;
#pragma unroll
        for (int it = 0; it < ITERS; ++it) {
            v4f w = __builtin_nontemporal_load(Wrow + it * 64 + lane);
            racc += w.x * q[it].x + w.y * q[it].y + w.z * q[it].z + w.w * q[it].w;
        }
        if (r & 1) acc1 += s01 * racc;
        else       acc0 += s01 * racc;
    }
    float acc = acc0 + acc1;

    // wave64 reduce, then 4 waves -> 1 value, pure store
    for (int off = 32; off; off >>= 1)
        acc += __shfl_down(acc, off, 64);

    __shared__ float wsum[BLOCK / 64];
    if (lane == 0) wsum[wid] = acc;
    __syncthreads();
    if (threadIdx.x == 0)
        ws[c * CHUNKS + chunk] = wsum[0] + wsum[1] + wsum[2] + wsum[3];
}

__global__ void vcdn_finalize(const float* __restrict__ ws,
                              const float* __restrict__ b,
                              float* __restrict__ out) {
    __shared__ float s[BLOCK];
    const int t   = threadIdx.x;
    const int c   = t >> 4;        // 16 threads per class
    const int sub = t & 15;
    float sum = 0.0f;
    for (int k = sub; k < CHUNKS; k += 16)     // 96/16 = 6 partials each
        sum += ws[c * CHUNKS + k];
    s[t] = sum;
    __syncthreads();
    if (t < N_CLASSES) {
        float tot = 0.0f;
#pragma unroll
        for (int k = 0; k < 16; ++k) tot += s[t * 16 + k];
        tot += b[t];
        out[t] = tot > 0.0f ? tot : 0.0f;
    }
}

extern "C" void kernel_launch(void* const* d_in, const int* in_sizes, int n_in,
                              void* d_out, int out_size, void* d_ws, size_t ws_size,
                              hipStream_t stream) {
    const float* x = (const float*)d_in[0];   // (4, 48) fp32
    const float* W = (const float*)d_in[1];   // (16, D) fp32
    const float* b = (const float*)d_in[2];   // (16,) fp32
    float* out = (float*)d_out;               // (16,) fp32
    float* ws  = (float*)d_ws;                // partials: 16*96 floats

    vcdn_main<<<N_CLASSES * CHUNKS, BLOCK, 0, stream>>>(x, W, ws);
    vcdn_finalize<<<1, BLOCK, 0, stream>>>(ws, b, out);
}